// Round 16
// baseline (268.867 us; speedup 1.0000x reference)
//
#include <hip/hip_runtime.h>

// SwinV2 window attention — round 16: TRUE <=128-total-regs push.
// m69: occupancy buckets are 64/128/256 total regs -> only <=128 gives
// 4 waves/SIMD. R14's swap-trick + full q/k/v pass split (32 AGPR each) +
// vT parked in the dead xt region (saves 16 persistent VGPR) fits ~110 total
// under __launch_bounds__(512,4). Spill tell: WRITE>160MB.
// ws layout: [0,128K) biasfrag f32 (SWAPPED frag order) | [128K,512K) w_t
//   fp16[768][256] | [512K,640K) p_t fp16[256][256]

typedef _Float16 f16;
typedef _Float16 f16x4 __attribute__((ext_vector_type(4)));
typedef _Float16 f16x8 __attribute__((ext_vector_type(8)));
typedef float f32x4 __attribute__((ext_vector_type(4)));

#define LOG100 4.6051701859880914f
#define EPS_L2 1.55e-5f

__device__ __forceinline__ int seg2(int p) { return (p >= 248) + (p >= 252); }

// ---------------- prep: CPB bias (SWAPPED MFMA C-frag order) + weight transpose
__global__ __launch_bounds__(512) void k_prep(
    const float* __restrict__ cpb_w1, const float* __restrict__ cpb_b1,
    const float* __restrict__ cpb_w2, const float* __restrict__ qkv_w,
    const float* __restrict__ proj_w,
    float* __restrict__ biasfrag, f16* __restrict__ w_t, f16* __restrict__ p_t)
{
    int tid = threadIdx.x;
    if (blockIdx.x == 0) {
        __shared__ float Lw1[1024];
        __shared__ float Lb1[512];
        __shared__ float Lw2[4096];
        __shared__ float part[450 * 8];
        __shared__ float cpb[225 * 8];
        #pragma unroll
        for (int i = tid; i < 1024; i += 512) Lw1[i] = cpb_w1[i];
        if (tid < 512) Lb1[tid] = cpb_b1[tid];
        #pragma unroll
        for (int i = tid; i < 4096; i += 512) Lw2[i] = cpb_w2[i];
        __syncthreads();
        {
            int e = tid >> 1, half = tid & 1;
            if (e < 225) {
                int a = e / 15, b2 = e % 15;
                float xa = (float)(a - 7) * (8.0f / 7.0f);
                float xb = (float)(b2 - 7) * (8.0f / 7.0f);
                float t0 = (xa < 0.f ? -1.f : 1.f) * log2f(1.0f + fabsf(xa)) * (1.0f / 3.0f);
                float t1 = (xb < 0.f ? -1.f : 1.f) * log2f(1.0f + fabsf(xb)) * (1.0f / 3.0f);
                float acc[8] = {0.f, 0.f, 0.f, 0.f, 0.f, 0.f, 0.f, 0.f};
                int j0 = half << 8;
                #pragma unroll 4
                for (int j = j0; j < j0 + 256; ++j) {
                    float hh = fmaxf(t0 * Lw1[j] + t1 * Lw1[512 + j] + Lb1[j], 0.0f);
                    #pragma unroll
                    for (int h = 0; h < 8; ++h) acc[h] += hh * Lw2[j * 8 + h];
                }
                #pragma unroll
                for (int h = 0; h < 8; ++h) part[tid * 8 + h] = acc[h];
            }
        }
        __syncthreads();
        if (tid < 225) {
            #pragma unroll
            for (int h = 0; h < 8; ++h)
                cpb[tid * 8 + h] = part[tid * 16 + h] + part[tid * 16 + 8 + h];
        }
        __syncthreads();
        // SWAPPED: frag holds S^T -> q from (lane&15, nt), k from (g,r, mt)
        for (int f = tid; f < 32768; f += 512) {
            int r = f & 3, lane = (f >> 2) & 63, nt = (f >> 8) & 3, mt = (f >> 10) & 3, h = (f >> 12) & 7;
            int k = mt * 16 + ((lane >> 4) << 2) + r;
            int q = nt * 16 + (lane & 15);
            int idx = ((q >> 3) - (k >> 3) + 7) * 15 + ((q & 7) - (k & 7) + 7);
            float c = cpb[idx * 8 + h];
            biasfrag[f] = 16.0f / (1.0f + expf(-c));
        }
    } else {
        int base = (blockIdx.x - 1) * 512 + tid;
        const int stride = 128 * 512;
        for (int i = base; i < 768 * 256; i += stride) {
            int n = i >> 8, k = i & 255;
            w_t[i] = (f16)qkv_w[k * 768 + n];     // w_t[n][k] = W[k][n]
        }
        for (int i = base; i < 256 * 256; i += stride) {
            int n = i >> 8, k = i & 255;
            p_t[i] = (f16)proj_w[k * 256 + n];
        }
    }
}

// ---------------- fused main: block = window, wave = head.
// LDS: [0,32K) xt[64 pix][256 ch] (GEMM) -> per-wave 4K vT slices (PV) -> ot (proj)
//      [32K,64K) 8 x 4K wave-private bounce (q/k frags, then P chunks)
__global__ __launch_bounds__(512, 4) void k_fused(
    const float* __restrict__ x, const f16* __restrict__ w_t,
    const float* __restrict__ q_bias, const float* __restrict__ v_bias,
    const float* __restrict__ scale, const float* __restrict__ biasfrag,
    const f16* __restrict__ p_t, const float* __restrict__ proj_b,
    float* __restrict__ out)
{
    __shared__ char L[65536];
    const int tid = threadIdx.x;
    const int lane = tid & 63;
    const int h = tid >> 6;                   // wave = head
    const int l15 = lane & 15, g = lane >> 4;
    const int bw = blockIdx.x;
    const int win = bw & 1023, b = bw >> 10;
    const int wh = win >> 5, ww = win & 31;
    char* wb = L + 32768 + (h << 12);         // wave bounce
    char* vtr = L + (h << 12);                // wave vT slice (xt region, dead after GEMM)
    const f32x4 fz = {0.f, 0.f, 0.f, 0.f};
    const bool boundary = (wh == 31) || (ww == 31);

    // ---- phase 0: stage the window's 64 pixels (rolled coords), f32->f16
    {
        int pos = tid >> 3, tc = tid & 7;
        int i2 = ((wh << 3) + (pos >> 3) + 4) & 255;
        int j2 = ((ww << 3) + (pos & 7) + 4) & 255;
        const float* xr = x + ((((long)b << 8) + i2) * 256 + j2) * 256;
        int swz = (pos & 7) << 4;
        #pragma unroll
        for (int rep = 0; rep < 4; ++rep) {
            int ch = rep * 64 + tc * 8;
            float4 v0 = *reinterpret_cast<const float4*>(xr + ch);
            float4 v1 = *reinterpret_cast<const float4*>(xr + ch + 4);
            f16x8 hv = { (f16)v0.x, (f16)v0.y, (f16)v0.z, (f16)v0.w,
                         (f16)v1.x, (f16)v1.y, (f16)v1.z, (f16)v1.w };
            *reinterpret_cast<f16x8*>(L + ((pos * 512 + ch * 2) ^ swz)) = hv;
        }
    }
    __syncthreads();   // barrier 1

    f16x8 qa[4], kb[4];

    // swapped GEMM pass for q or k: acc[ct][mt] = C[ch, pix]; 32 AGPR peak
    auto qk_pass = [&](int p, float ls, bool addb, f16x8 frag[4]) {
        f32x4 acc[2][4];
        #pragma unroll
        for (int i = 0; i < 2; ++i)
            #pragma unroll
            for (int j = 0; j < 4; ++j) acc[i][j] = fz;
        #pragma unroll
        for (int ks = 0; ks < 8; ++ks) {
            f16x8 xf[4], wf[2];
            #pragma unroll
            for (int mt = 0; mt < 4; ++mt) {
                int row = mt * 16 + l15;
                xf[mt] = *reinterpret_cast<const f16x8*>(
                    L + ((row * 512 + ks * 64 + g * 16) ^ ((row & 7) << 4)));
            }
            #pragma unroll
            for (int ct = 0; ct < 2; ++ct)
                wf[ct] = *reinterpret_cast<const f16x8*>(
                    w_t + ((p << 8) + (h << 5) + ct * 16 + l15) * 256 + ks * 32 + g * 8);
            #pragma unroll
            for (int ct = 0; ct < 2; ++ct)
                #pragma unroll
                for (int mt = 0; mt < 4; ++mt)
                    acc[ct][mt] = __builtin_amdgcn_mfma_f32_16x16x32_f16(wf[ct], xf[mt], acc[ct][mt], 0, 0, 0);
        }
        float qb0[4], qb1[4];
        #pragma unroll
        for (int r = 0; r < 4; ++r) {
            qb0[r] = addb ? q_bias[(h << 5) + (g << 2) + r] : 0.f;
            qb1[r] = addb ? q_bias[(h << 5) + 16 + (g << 2) + r] : 0.f;
        }
        #pragma unroll
        for (int nt = 0; nt < 4; ++nt) {
            int pix = nt * 16 + l15;
            float t0[4], t1[4], s2 = 0.f;
            #pragma unroll
            for (int r = 0; r < 4; ++r) {
                t0[r] = acc[0][nt][r] + qb0[r];
                t1[r] = acc[1][nt][r] + qb1[r];
                s2 += t0[r] * t0[r] + t1[r] * t1[r];
            }
            s2 += __shfl_xor(s2, 16); s2 += __shfl_xor(s2, 32);
            float iv = ls / sqrtf(fmaxf(s2, EPS_L2));
            int sw = (pix & 7) << 4;
            f16x4 p0 = { (f16)(t0[0] * iv), (f16)(t0[1] * iv), (f16)(t0[2] * iv), (f16)(t0[3] * iv) };
            f16x4 p1 = { (f16)(t1[0] * iv), (f16)(t1[1] * iv), (f16)(t1[2] * iv), (f16)(t1[3] * iv) };
            *reinterpret_cast<f16x4*>(wb + ((pix * 64 + (g << 3)) ^ sw)) = p0;
            *reinterpret_cast<f16x4*>(wb + ((pix * 64 + 32 + (g << 3)) ^ sw)) = p1;
        }
        #pragma unroll
        for (int nt = 0; nt < 4; ++nt)
            frag[nt] = *reinterpret_cast<const f16x8*>(
                wb + (((nt * 16 + l15) * 64 + g * 16) ^ ((l15 & 7) << 4)));
    };

    // ---- phase 1a/1b: q then k (32 AGPR each)
    qk_pass(0, __expf(fminf(scale[h], LOG100)), true, qa);
    qk_pass(1, 1.0f, false, kb);

    // ---- phase 1c: v GEMM (normal orient, 32 AGPR); vT -> xt-region slice
    f16x8 vf[2][2];
    {
        f32x4 av[4][2];
        #pragma unroll
        for (int mt = 0; mt < 4; ++mt) { av[mt][0] = fz; av[mt][1] = fz; }
        #pragma unroll
        for (int ks = 0; ks < 8; ++ks) {
            f16x8 xf[4], wv[2];
            #pragma unroll
            for (int mt = 0; mt < 4; ++mt) {
                int row = mt * 16 + l15;
                xf[mt] = *reinterpret_cast<const f16x8*>(
                    L + ((row * 512 + ks * 64 + g * 16) ^ ((row & 7) << 4)));
            }
            #pragma unroll
            for (int nt = 0; nt < 2; ++nt)
                wv[nt] = *reinterpret_cast<const f16x8*>(
                    w_t + (512 + (h << 5) + nt * 16 + l15) * 256 + ks * 32 + g * 8);
            #pragma unroll
            for (int mt = 0; mt < 4; ++mt)
                #pragma unroll
                for (int nt = 0; nt < 2; ++nt)
                    av[mt][nt] = __builtin_amdgcn_mfma_f32_16x16x32_f16(xf[mt], wv[nt], av[mt][nt], 0, 0, 0);
        }
        __syncthreads();   // barrier 2: ALL xt reads done; xt region becomes vT
        float b0 = v_bias[(h << 5) + l15], b1 = v_bias[(h << 5) + 16 + l15];
        #pragma unroll
        for (int mt = 0; mt < 4; ++mt)
            #pragma unroll
            for (int nt = 0; nt < 2; ++nt) {
                float bsel = nt ? b1 : b0;
                f32x4 avv = av[mt][nt];
                f16x4 pk = { (f16)(avv[0] + bsel), (f16)(avv[1] + bsel),
                             (f16)(avv[2] + bsel), (f16)(avv[3] + bsel) };
                int u = nt * 16 + l15;
                int pix0 = mt * 16 + (g << 2);
                *reinterpret_cast<f16x4*>(vtr + ((u * 128 + pix0 * 2) ^ ((u & 7) << 4))) = pk;
            }
        #pragma unroll
        for (int nt = 0; nt < 2; ++nt)
            #pragma unroll
            for (int ks = 0; ks < 2; ++ks)
                vf[nt][ks] = *reinterpret_cast<const f16x8*>(
                    vtr + (((nt * 16 + l15) * 128 + ks * 64 + g * 16) ^ ((l15 & 7) << 4)));
    }

    // ---- phase 2: S^T = mfma(K,Q); lane-local softmax; P chunked 32 q-rows
    f16x4 oh[4][2];
    #pragma unroll
    for (int c = 0; c < 2; ++c) {
        #pragma unroll
        for (int n2 = 0; n2 < 2; ++n2) {
            const int nt = c * 2 + n2;
            const int qrow = nt * 16 + l15;
            f32x4 st[4];
            #pragma unroll
            for (int mt = 0; mt < 4; ++mt)
                st[mt] = __builtin_amdgcn_mfma_f32_16x16x32_f16(kb[mt], qa[nt], fz, 0, 0, 0);
            #pragma unroll
            for (int mt = 0; mt < 4; ++mt)
                st[mt] += *reinterpret_cast<const f32x4*>(
                    biasfrag + ((((h * 4 + mt) * 4 + nt) * 64 + lane) << 2));
            if (boundary) {
                int lq = seg2((wh << 3) + (qrow >> 3)) * 3 + seg2((ww << 3) + (qrow & 7));
                #pragma unroll
                for (int mt = 0; mt < 4; ++mt)
                    #pragma unroll
                    for (int r = 0; r < 4; ++r) {
                        int k = mt * 16 + (g << 2) + r;
                        int lk = seg2((wh << 3) + (k >> 3)) * 3 + seg2((ww << 3) + (k & 7));
                        if (lq != lk) st[mt][r] -= 100.0f;
                    }
            }
            float mx = st[0][0];
            #pragma unroll
            for (int mt = 0; mt < 4; ++mt)
                #pragma unroll
                for (int r = 0; r < 4; ++r) mx = fmaxf(mx, st[mt][r]);
            mx = fmaxf(mx, __shfl_xor(mx, 16));
            mx = fmaxf(mx, __shfl_xor(mx, 32));
            float sm = 0.f;
            #pragma unroll
            for (int mt = 0; mt < 4; ++mt)
                #pragma unroll
                for (int r = 0; r < 4; ++r) {
                    float e = __expf(st[mt][r] - mx);
                    st[mt][r] = e;
                    sm += e;
                }
            sm += __shfl_xor(sm, 16);
            sm += __shfl_xor(sm, 32);
            float inv = 1.0f / sm;
            int sw = (qrow & 7) << 4;
            int rowb = (qrow & 31) * 128;     // local row in 4KB chunk
            #pragma unroll
            for (int mt = 0; mt < 4; ++mt) {
                f16x4 pk = { (f16)(st[mt][0] * inv), (f16)(st[mt][1] * inv),
                             (f16)(st[mt][2] * inv), (f16)(st[mt][3] * inv) };
                *reinterpret_cast<f16x4*>(wb + ((rowb + mt * 32 + (g << 3)) ^ sw)) = pk;
            }
        }
        // PV for this chunk (q-row tiles c*2, c*2+1)
        #pragma unroll
        for (int m2 = 0; m2 < 2; ++m2) {
            const int mt = c * 2 + m2;
            int row = m2 * 16 + l15;
            int swz = (row & 7) << 4;
            f16x8 pa0 = *reinterpret_cast<const f16x8*>(wb + ((row * 128 + g * 16) ^ swz));
            f16x8 pa1 = *reinterpret_cast<const f16x8*>(wb + ((row * 128 + 64 + g * 16) ^ swz));
            #pragma unroll
            for (int nt = 0; nt < 2; ++nt) {
                f32x4 t = __builtin_amdgcn_mfma_f32_16x16x32_f16(pa0, vf[nt][0], fz, 0, 0, 0);
                t = __builtin_amdgcn_mfma_f32_16x16x32_f16(pa1, vf[nt][1], t, 0, 0, 0);
                oh[mt][nt] = f16x4{ (f16)t[0], (f16)t[1], (f16)t[2], (f16)t[3] };
            }
        }
    }

    // ---- phase 3: O -> ot (xt region), fused proj, direct store
    __syncthreads();   // barrier 3: all PV done; vT region becomes ot
    #pragma unroll
    for (int mt = 0; mt < 4; ++mt)
        #pragma unroll
        for (int r = 0; r < 4; ++r) {
            int q = mt * 16 + (g << 2) + r;
            #pragma unroll
            for (int nt = 0; nt < 2; ++nt) {
                int ch = (h << 5) + nt * 16 + l15;
                *reinterpret_cast<f16*>(L + ((q * 512 + ch * 2) ^ ((q & 7) << 4))) =
                    oh[mt][nt][r];
            }
        }
    __syncthreads();   // barrier 4

    const int c0 = h << 5;
    f32x4 pc[4][2];
    #pragma unroll
    for (int mt = 0; mt < 4; ++mt) { pc[mt][0] = fz; pc[mt][1] = fz; }
    #pragma unroll
    for (int ks = 0; ks < 8; ++ks) {
        f16x8 a[4], bfr[2];
        #pragma unroll
        for (int mt = 0; mt < 4; ++mt) {
            int q = mt * 16 + l15;
            a[mt] = *reinterpret_cast<const f16x8*>(
                L + ((q * 512 + ks * 64 + g * 16) ^ ((q & 7) << 4)));
        }
        #pragma unroll
        for (int nt = 0; nt < 2; ++nt)
            bfr[nt] = *reinterpret_cast<const f16x8*>(
                p_t + (c0 + nt * 16 + l15) * 256 + ks * 32 + g * 8);
        #pragma unroll
        for (int mt = 0; mt < 4; ++mt)
            #pragma unroll
            for (int nt = 0; nt < 2; ++nt)
                pc[mt][nt] = __builtin_amdgcn_mfma_f32_16x16x32_f16(a[mt], bfr[nt], pc[mt][nt], 0, 0, 0);
    }
    float pb0 = proj_b[c0 + l15], pb1 = proj_b[c0 + 16 + l15];
    #pragma unroll
    for (int mt = 0; mt < 4; ++mt)
        #pragma unroll
        for (int r = 0; r < 4; ++r) {
            int q = mt * 16 + (g << 2) + r;
            int i = ((wh << 3) + (q >> 3) + 4) & 255;   // roll(+4) un-partition
            int j = ((ww << 3) + (q & 7) + 4) & 255;
            long addr = (((long)b * 256 + i) * 256 + j) * 256;
            out[addr + c0 + l15]      = pc[mt][0][r] + pb0;
            out[addr + c0 + 16 + l15] = pc[mt][1][r] + pb1;
        }
}

extern "C" void kernel_launch(void* const* d_in, const int* in_sizes, int n_in,
                              void* d_out, int out_size, void* d_ws, size_t ws_size,
                              hipStream_t stream) {
    const float* x      = (const float*)d_in[0];
    const float* qkv_w  = (const float*)d_in[1];
    const float* q_bias = (const float*)d_in[2];
    const float* v_bias = (const float*)d_in[3];
    const float* scale  = (const float*)d_in[4];
    const float* cpb_w1 = (const float*)d_in[5];
    const float* cpb_b1 = (const float*)d_in[6];
    const float* cpb_w2 = (const float*)d_in[7];
    const float* proj_w = (const float*)d_in[8];
    const float* proj_b = (const float*)d_in[9];
    float* out = (float*)d_out;

    char* ws = (char*)d_ws;
    float* biasfrag = (float*)(ws);                         // 128 KiB
    f16* w_t  = (f16*)(ws + 131072);                        // 384 KiB
    f16* p_t  = (f16*)(ws + 524288);                        // 128 KiB

    hipLaunchKernelGGL(k_prep, dim3(129), dim3(512), 0, stream,
                       cpb_w1, cpb_b1, cpb_w2, qkv_w, proj_w, biasfrag, w_t, p_t);
    hipLaunchKernelGGL(k_fused, dim3(2048), dim3(512), 0, stream,
                       x, w_t, q_bias, v_bias, scale, biasfrag, p_t, proj_b, out);
}

// Round 17
// 247.410 us; speedup vs baseline: 1.0867x; 1.0867x over previous
//
#include <hip/hip_runtime.h>

// SwinV2 window attention — round 17: natural <=128-total-reg attempt.
// Lesson R12/R16: __launch_bounds__(512,4) makes the compiler hard-split
// 64 VGPR + 64 AGPR and spill (~250MB). Here: NO min-waves bound (compiler
// free), per-pass AGPR=32 (split passes), vf de-persisted (reload per PV
// chunk from vtr). If natural VGPR+AGPR <=128, occupancy doubles for free.
// ws layout: [0,128K) biasfrag f32 (SWAPPED frag order) | [128K,512K) w_t
//   fp16[768][256] | [512K,640K) p_t fp16[256][256]

typedef _Float16 f16;
typedef _Float16 f16x4 __attribute__((ext_vector_type(4)));
typedef _Float16 f16x8 __attribute__((ext_vector_type(8)));
typedef float f32x4 __attribute__((ext_vector_type(4)));

#define LOG100 4.6051701859880914f
#define EPS_L2 1.55e-5f

__device__ __forceinline__ int seg2(int p) { return (p >= 248) + (p >= 252); }

// ---------------- prep: CPB bias (SWAPPED MFMA C-frag order) + weight transpose
__global__ __launch_bounds__(512) void k_prep(
    const float* __restrict__ cpb_w1, const float* __restrict__ cpb_b1,
    const float* __restrict__ cpb_w2, const float* __restrict__ qkv_w,
    const float* __restrict__ proj_w,
    float* __restrict__ biasfrag, f16* __restrict__ w_t, f16* __restrict__ p_t)
{
    int tid = threadIdx.x;
    if (blockIdx.x == 0) {
        __shared__ float Lw1[1024];
        __shared__ float Lb1[512];
        __shared__ float Lw2[4096];
        __shared__ float part[450 * 8];
        __shared__ float cpb[225 * 8];
        #pragma unroll
        for (int i = tid; i < 1024; i += 512) Lw1[i] = cpb_w1[i];
        if (tid < 512) Lb1[tid] = cpb_b1[tid];
        #pragma unroll
        for (int i = tid; i < 4096; i += 512) Lw2[i] = cpb_w2[i];
        __syncthreads();
        {
            int e = tid >> 1, half = tid & 1;
            if (e < 225) {
                int a = e / 15, b2 = e % 15;
                float xa = (float)(a - 7) * (8.0f / 7.0f);
                float xb = (float)(b2 - 7) * (8.0f / 7.0f);
                float t0 = (xa < 0.f ? -1.f : 1.f) * log2f(1.0f + fabsf(xa)) * (1.0f / 3.0f);
                float t1 = (xb < 0.f ? -1.f : 1.f) * log2f(1.0f + fabsf(xb)) * (1.0f / 3.0f);
                float acc[8] = {0.f, 0.f, 0.f, 0.f, 0.f, 0.f, 0.f, 0.f};
                int j0 = half << 8;
                #pragma unroll 4
                for (int j = j0; j < j0 + 256; ++j) {
                    float hh = fmaxf(t0 * Lw1[j] + t1 * Lw1[512 + j] + Lb1[j], 0.0f);
                    #pragma unroll
                    for (int h = 0; h < 8; ++h) acc[h] += hh * Lw2[j * 8 + h];
                }
                #pragma unroll
                for (int h = 0; h < 8; ++h) part[tid * 8 + h] = acc[h];
            }
        }
        __syncthreads();
        if (tid < 225) {
            #pragma unroll
            for (int h = 0; h < 8; ++h)
                cpb[tid * 8 + h] = part[tid * 16 + h] + part[tid * 16 + 8 + h];
        }
        __syncthreads();
        // SWAPPED: frag holds S^T -> q from (lane&15, nt), k from (g,r, mt)
        for (int f = tid; f < 32768; f += 512) {
            int r = f & 3, lane = (f >> 2) & 63, nt = (f >> 8) & 3, mt = (f >> 10) & 3, h = (f >> 12) & 7;
            int k = mt * 16 + ((lane >> 4) << 2) + r;
            int q = nt * 16 + (lane & 15);
            int idx = ((q >> 3) - (k >> 3) + 7) * 15 + ((q & 7) - (k & 7) + 7);
            float c = cpb[idx * 8 + h];
            biasfrag[f] = 16.0f / (1.0f + expf(-c));
        }
    } else {
        int base = (blockIdx.x - 1) * 512 + tid;
        const int stride = 128 * 512;
        for (int i = base; i < 768 * 256; i += stride) {
            int n = i >> 8, k = i & 255;
            w_t[i] = (f16)qkv_w[k * 768 + n];     // w_t[n][k] = W[k][n]
        }
        for (int i = base; i < 256 * 256; i += stride) {
            int n = i >> 8, k = i & 255;
            p_t[i] = (f16)proj_w[k * 256 + n];
        }
    }
}

// ---------------- fused main: block = window, wave = head.
// LDS: [0,32K) xt[64 pix][256 ch] (GEMM) -> per-wave 4K vT slices (PV) -> ot (proj)
//      [32K,64K) 8 x 4K wave-private bounce (q/k frags, then P chunks)
__global__ __launch_bounds__(512) void k_fused(
    const float* __restrict__ x, const f16* __restrict__ w_t,
    const float* __restrict__ q_bias, const float* __restrict__ v_bias,
    const float* __restrict__ scale, const float* __restrict__ biasfrag,
    const f16* __restrict__ p_t, const float* __restrict__ proj_b,
    float* __restrict__ out)
{
    __shared__ char L[65536];
    const int tid = threadIdx.x;
    const int lane = tid & 63;
    const int h = tid >> 6;                   // wave = head
    const int l15 = lane & 15, g = lane >> 4;
    const int bw = blockIdx.x;
    const int win = bw & 1023, b = bw >> 10;
    const int wh = win >> 5, ww = win & 31;
    char* wb = L + 32768 + (h << 12);         // wave bounce
    char* vtr = L + (h << 12);                // wave vT slice (xt region, dead after GEMM)
    const f32x4 fz = {0.f, 0.f, 0.f, 0.f};
    const bool boundary = (wh == 31) || (ww == 31);

    // ---- phase 0: stage the window's 64 pixels (rolled coords), f32->f16
    {
        int pos = tid >> 3, tc = tid & 7;
        int i2 = ((wh << 3) + (pos >> 3) + 4) & 255;
        int j2 = ((ww << 3) + (pos & 7) + 4) & 255;
        const float* xr = x + ((((long)b << 8) + i2) * 256 + j2) * 256;
        int swz = (pos & 7) << 4;
        #pragma unroll
        for (int rep = 0; rep < 4; ++rep) {
            int ch = rep * 64 + tc * 8;
            float4 v0 = *reinterpret_cast<const float4*>(xr + ch);
            float4 v1 = *reinterpret_cast<const float4*>(xr + ch + 4);
            f16x8 hv = { (f16)v0.x, (f16)v0.y, (f16)v0.z, (f16)v0.w,
                         (f16)v1.x, (f16)v1.y, (f16)v1.z, (f16)v1.w };
            *reinterpret_cast<f16x8*>(L + ((pos * 512 + ch * 2) ^ swz)) = hv;
        }
    }
    __syncthreads();   // barrier 1

    f16x8 qa[4], kb[4];

    // swapped GEMM pass for q or k: acc[ct][mt] = C[ch, pix]; 32 AGPR peak
    auto qk_pass = [&](int p, float ls, bool addb, f16x8 frag[4]) {
        f32x4 acc[2][4];
        #pragma unroll
        for (int i = 0; i < 2; ++i)
            #pragma unroll
            for (int j = 0; j < 4; ++j) acc[i][j] = fz;
        #pragma unroll
        for (int ks = 0; ks < 8; ++ks) {
            f16x8 xf[4], wf[2];
            #pragma unroll
            for (int mt = 0; mt < 4; ++mt) {
                int row = mt * 16 + l15;
                xf[mt] = *reinterpret_cast<const f16x8*>(
                    L + ((row * 512 + ks * 64 + g * 16) ^ ((row & 7) << 4)));
            }
            #pragma unroll
            for (int ct = 0; ct < 2; ++ct)
                wf[ct] = *reinterpret_cast<const f16x8*>(
                    w_t + ((p << 8) + (h << 5) + ct * 16 + l15) * 256 + ks * 32 + g * 8);
            #pragma unroll
            for (int ct = 0; ct < 2; ++ct)
                #pragma unroll
                for (int mt = 0; mt < 4; ++mt)
                    acc[ct][mt] = __builtin_amdgcn_mfma_f32_16x16x32_f16(wf[ct], xf[mt], acc[ct][mt], 0, 0, 0);
        }
        float qb0[4], qb1[4];
        #pragma unroll
        for (int r = 0; r < 4; ++r) {
            qb0[r] = addb ? q_bias[(h << 5) + (g << 2) + r] : 0.f;
            qb1[r] = addb ? q_bias[(h << 5) + 16 + (g << 2) + r] : 0.f;
        }
        #pragma unroll
        for (int nt = 0; nt < 4; ++nt) {
            int pix = nt * 16 + l15;
            float t0[4], t1[4], s2 = 0.f;
            #pragma unroll
            for (int r = 0; r < 4; ++r) {
                t0[r] = acc[0][nt][r] + qb0[r];
                t1[r] = acc[1][nt][r] + qb1[r];
                s2 += t0[r] * t0[r] + t1[r] * t1[r];
            }
            s2 += __shfl_xor(s2, 16); s2 += __shfl_xor(s2, 32);
            float iv = ls / sqrtf(fmaxf(s2, EPS_L2));
            int sw = (pix & 7) << 4;
            f16x4 p0 = { (f16)(t0[0] * iv), (f16)(t0[1] * iv), (f16)(t0[2] * iv), (f16)(t0[3] * iv) };
            f16x4 p1 = { (f16)(t1[0] * iv), (f16)(t1[1] * iv), (f16)(t1[2] * iv), (f16)(t1[3] * iv) };
            *reinterpret_cast<f16x4*>(wb + ((pix * 64 + (g << 3)) ^ sw)) = p0;
            *reinterpret_cast<f16x4*>(wb + ((pix * 64 + 32 + (g << 3)) ^ sw)) = p1;
        }
        #pragma unroll
        for (int nt = 0; nt < 4; ++nt)
            frag[nt] = *reinterpret_cast<const f16x8*>(
                wb + (((nt * 16 + l15) * 64 + g * 16) ^ ((l15 & 7) << 4)));
    };

    // ---- phase 1a/1b: q then k (32 AGPR each)
    qk_pass(0, __expf(fminf(scale[h], LOG100)), true, qa);
    qk_pass(1, 1.0f, false, kb);

    // ---- phase 1c: v GEMM (normal orient, 32 AGPR); vT -> xt-region slice
    {
        f32x4 av[4][2];
        #pragma unroll
        for (int mt = 0; mt < 4; ++mt) { av[mt][0] = fz; av[mt][1] = fz; }
        #pragma unroll
        for (int ks = 0; ks < 8; ++ks) {
            f16x8 xf[4], wv[2];
            #pragma unroll
            for (int mt = 0; mt < 4; ++mt) {
                int row = mt * 16 + l15;
                xf[mt] = *reinterpret_cast<const f16x8*>(
                    L + ((row * 512 + ks * 64 + g * 16) ^ ((row & 7) << 4)));
            }
            #pragma unroll
            for (int nt = 0; nt < 2; ++nt)
                wv[nt] = *reinterpret_cast<const f16x8*>(
                    w_t + (512 + (h << 5) + nt * 16 + l15) * 256 + ks * 32 + g * 8);
            #pragma unroll
            for (int mt = 0; mt < 4; ++mt)
                #pragma unroll
                for (int nt = 0; nt < 2; ++nt)
                    av[mt][nt] = __builtin_amdgcn_mfma_f32_16x16x32_f16(xf[mt], wv[nt], av[mt][nt], 0, 0, 0);
        }
        __syncthreads();   // barrier 2: ALL xt reads done; xt region becomes vT
        float b0 = v_bias[(h << 5) + l15], b1 = v_bias[(h << 5) + 16 + l15];
        #pragma unroll
        for (int mt = 0; mt < 4; ++mt)
            #pragma unroll
            for (int nt = 0; nt < 2; ++nt) {
                float bsel = nt ? b1 : b0;
                f32x4 avv = av[mt][nt];
                f16x4 pk = { (f16)(avv[0] + bsel), (f16)(avv[1] + bsel),
                             (f16)(avv[2] + bsel), (f16)(avv[3] + bsel) };
                int u = nt * 16 + l15;
                int pix0 = mt * 16 + (g << 2);
                *reinterpret_cast<f16x4*>(vtr + ((u * 128 + pix0 * 2) ^ ((u & 7) << 4))) = pk;
            }
    }

    // ---- phase 2: S^T = mfma(K,Q); lane-local softmax; P chunked 32 q-rows
    f16x4 oh[4][2];
    #pragma unroll
    for (int c = 0; c < 2; ++c) {
        #pragma unroll
        for (int n2 = 0; n2 < 2; ++n2) {
            const int nt = c * 2 + n2;
            const int qrow = nt * 16 + l15;
            f32x4 st[4];
            #pragma unroll
            for (int mt = 0; mt < 4; ++mt)
                st[mt] = __builtin_amdgcn_mfma_f32_16x16x32_f16(kb[mt], qa[nt], fz, 0, 0, 0);
            #pragma unroll
            for (int mt = 0; mt < 4; ++mt)
                st[mt] += *reinterpret_cast<const f32x4*>(
                    biasfrag + ((((h * 4 + mt) * 4 + nt) * 64 + lane) << 2));
            if (boundary) {
                int lq = seg2((wh << 3) + (qrow >> 3)) * 3 + seg2((ww << 3) + (qrow & 7));
                #pragma unroll
                for (int mt = 0; mt < 4; ++mt)
                    #pragma unroll
                    for (int r = 0; r < 4; ++r) {
                        int k = mt * 16 + (g << 2) + r;
                        int lk = seg2((wh << 3) + (k >> 3)) * 3 + seg2((ww << 3) + (k & 7));
                        if (lq != lk) st[mt][r] -= 100.0f;
                    }
            }
            float mx = st[0][0];
            #pragma unroll
            for (int mt = 0; mt < 4; ++mt)
                #pragma unroll
                for (int r = 0; r < 4; ++r) mx = fmaxf(mx, st[mt][r]);
            mx = fmaxf(mx, __shfl_xor(mx, 16));
            mx = fmaxf(mx, __shfl_xor(mx, 32));
            float sm = 0.f;
            #pragma unroll
            for (int mt = 0; mt < 4; ++mt)
                #pragma unroll
                for (int r = 0; r < 4; ++r) {
                    float e = __expf(st[mt][r] - mx);
                    st[mt][r] = e;
                    sm += e;
                }
            sm += __shfl_xor(sm, 16);
            sm += __shfl_xor(sm, 32);
            float inv = 1.0f / sm;
            int sw = (qrow & 7) << 4;
            int rowb = (qrow & 31) * 128;     // local row in 4KB chunk
            #pragma unroll
            for (int mt = 0; mt < 4; ++mt) {
                f16x4 pk = { (f16)(st[mt][0] * inv), (f16)(st[mt][1] * inv),
                             (f16)(st[mt][2] * inv), (f16)(st[mt][3] * inv) };
                *reinterpret_cast<f16x4*>(wb + ((rowb + mt * 32 + (g << 3)) ^ sw)) = pk;
            }
        }
        // PV for this chunk (q-row tiles c*2, c*2+1); vf reloaded per chunk
        #pragma unroll
        for (int m2 = 0; m2 < 2; ++m2) {
            const int mt = c * 2 + m2;
            int row = m2 * 16 + l15;
            int swz = (row & 7) << 4;
            f16x8 pa0 = *reinterpret_cast<const f16x8*>(wb + ((row * 128 + g * 16) ^ swz));
            f16x8 pa1 = *reinterpret_cast<const f16x8*>(wb + ((row * 128 + 64 + g * 16) ^ swz));
            #pragma unroll
            for (int nt = 0; nt < 2; ++nt) {
                f16x8 vf0 = *reinterpret_cast<const f16x8*>(
                    vtr + (((nt * 16 + l15) * 128 + g * 16) ^ ((l15 & 7) << 4)));
                f16x8 vf1 = *reinterpret_cast<const f16x8*>(
                    vtr + (((nt * 16 + l15) * 128 + 64 + g * 16) ^ ((l15 & 7) << 4)));
                f32x4 t = __builtin_amdgcn_mfma_f32_16x16x32_f16(pa0, vf0, fz, 0, 0, 0);
                t = __builtin_amdgcn_mfma_f32_16x16x32_f16(pa1, vf1, t, 0, 0, 0);
                oh[mt][nt] = f16x4{ (f16)t[0], (f16)t[1], (f16)t[2], (f16)t[3] };
            }
        }
    }

    // ---- phase 3: O -> ot (xt region), fused proj, direct store
    __syncthreads();   // barrier 3: all PV done; vT region becomes ot
    #pragma unroll
    for (int mt = 0; mt < 4; ++mt)
        #pragma unroll
        for (int r = 0; r < 4; ++r) {
            int q = mt * 16 + (g << 2) + r;
            #pragma unroll
            for (int nt = 0; nt < 2; ++nt) {
                int ch = (h << 5) + nt * 16 + l15;
                *reinterpret_cast<f16*>(L + ((q * 512 + ch * 2) ^ ((q & 7) << 4))) =
                    oh[mt][nt][r];
            }
        }
    __syncthreads();   // barrier 4

    const int c0 = h << 5;
    f32x4 pc[4][2];
    #pragma unroll
    for (int mt = 0; mt < 4; ++mt) { pc[mt][0] = fz; pc[mt][1] = fz; }
    #pragma unroll
    for (int ks = 0; ks < 8; ++ks) {
        f16x8 a[4], bfr[2];
        #pragma unroll
        for (int mt = 0; mt < 4; ++mt) {
            int q = mt * 16 + l15;
            a[mt] = *reinterpret_cast<const f16x8*>(
                L + ((q * 512 + ks * 64 + g * 16) ^ ((q & 7) << 4)));
        }
        #pragma unroll
        for (int nt = 0; nt < 2; ++nt)
            bfr[nt] = *reinterpret_cast<const f16x8*>(
                p_t + (c0 + nt * 16 + l15) * 256 + ks * 32 + g * 8);
        #pragma unroll
        for (int mt = 0; mt < 4; ++mt)
            #pragma unroll
            for (int nt = 0; nt < 2; ++nt)
                pc[mt][nt] = __builtin_amdgcn_mfma_f32_16x16x32_f16(a[mt], bfr[nt], pc[mt][nt], 0, 0, 0);
    }
    float pb0 = proj_b[c0 + l15], pb1 = proj_b[c0 + 16 + l15];
    #pragma unroll
    for (int mt = 0; mt < 4; ++mt)
        #pragma unroll
        for (int r = 0; r < 4; ++r) {
            int q = mt * 16 + (g << 2) + r;
            int i = ((wh << 3) + (q >> 3) + 4) & 255;   // roll(+4) un-partition
            int j = ((ww << 3) + (q & 7) + 4) & 255;
            long addr = (((long)b * 256 + i) * 256 + j) * 256;
            out[addr + c0 + l15]      = pc[mt][0][r] + pb0;
            out[addr + c0 + 16 + l15] = pc[mt][1][r] + pb1;
        }
}

extern "C" void kernel_launch(void* const* d_in, const int* in_sizes, int n_in,
                              void* d_out, int out_size, void* d_ws, size_t ws_size,
                              hipStream_t stream) {
    const float* x      = (const float*)d_in[0];
    const float* qkv_w  = (const float*)d_in[1];
    const float* q_bias = (const float*)d_in[2];
    const float* v_bias = (const float*)d_in[3];
    const float* scale  = (const float*)d_in[4];
    const float* cpb_w1 = (const float*)d_in[5];
    const float* cpb_b1 = (const float*)d_in[6];
    const float* cpb_w2 = (const float*)d_in[7];
    const float* proj_w = (const float*)d_in[8];
    const float* proj_b = (const float*)d_in[9];
    float* out = (float*)d_out;

    char* ws = (char*)d_ws;
    float* biasfrag = (float*)(ws);                         // 128 KiB
    f16* w_t  = (f16*)(ws + 131072);                        // 384 KiB
    f16* p_t  = (f16*)(ws + 524288);                        // 128 KiB

    hipLaunchKernelGGL(k_prep, dim3(129), dim3(512), 0, stream,
                       cpb_w1, cpb_b1, cpb_w2, qkv_w, proj_w, biasfrag, w_t, p_t);
    hipLaunchKernelGGL(k_fused, dim3(2048), dim3(512), 0, stream,
                       x, w_t, q_bias, v_bias, scale, biasfrag, p_t, proj_b, out);
}

// Round 18
// 242.046 us; speedup vs baseline: 1.1108x; 1.0222x over previous
//
#include <hip/hip_runtime.h>

// SwinV2 window attention — round 18: R17 + sched_barrier(0) at phase
// boundaries. Hypothesis: scheduler overlaps passes -> concurrent AGPR ~64 ->
// total regs ~144 > 128 -> 2 waves/SIMD (23% occ) despite VGPR=80. Killing
// cross-pass scheduling caps AGPR at 32 -> total ~112 <= 128 -> 4 waves/SIMD,
// 2 blocks/CU, no forced cap (so no spill risk).
// ws layout: [0,128K) biasfrag f32 (SWAPPED frag order) | [128K,512K) w_t
//   fp16[768][256] | [512K,640K) p_t fp16[256][256]

typedef _Float16 f16;
typedef _Float16 f16x4 __attribute__((ext_vector_type(4)));
typedef _Float16 f16x8 __attribute__((ext_vector_type(8)));
typedef float f32x4 __attribute__((ext_vector_type(4)));

#define LOG100 4.6051701859880914f
#define EPS_L2 1.55e-5f

__device__ __forceinline__ int seg2(int p) { return (p >= 248) + (p >= 252); }

// ---------------- prep: CPB bias (SWAPPED MFMA C-frag order) + weight transpose
__global__ __launch_bounds__(512) void k_prep(
    const float* __restrict__ cpb_w1, const float* __restrict__ cpb_b1,
    const float* __restrict__ cpb_w2, const float* __restrict__ qkv_w,
    const float* __restrict__ proj_w,
    float* __restrict__ biasfrag, f16* __restrict__ w_t, f16* __restrict__ p_t)
{
    int tid = threadIdx.x;
    if (blockIdx.x == 0) {
        __shared__ float Lw1[1024];
        __shared__ float Lb1[512];
        __shared__ float Lw2[4096];
        __shared__ float part[450 * 8];
        __shared__ float cpb[225 * 8];
        #pragma unroll
        for (int i = tid; i < 1024; i += 512) Lw1[i] = cpb_w1[i];
        if (tid < 512) Lb1[tid] = cpb_b1[tid];
        #pragma unroll
        for (int i = tid; i < 4096; i += 512) Lw2[i] = cpb_w2[i];
        __syncthreads();
        {
            int e = tid >> 1, half = tid & 1;
            if (e < 225) {
                int a = e / 15, b2 = e % 15;
                float xa = (float)(a - 7) * (8.0f / 7.0f);
                float xb = (float)(b2 - 7) * (8.0f / 7.0f);
                float t0 = (xa < 0.f ? -1.f : 1.f) * log2f(1.0f + fabsf(xa)) * (1.0f / 3.0f);
                float t1 = (xb < 0.f ? -1.f : 1.f) * log2f(1.0f + fabsf(xb)) * (1.0f / 3.0f);
                float acc[8] = {0.f, 0.f, 0.f, 0.f, 0.f, 0.f, 0.f, 0.f};
                int j0 = half << 8;
                #pragma unroll 4
                for (int j = j0; j < j0 + 256; ++j) {
                    float hh = fmaxf(t0 * Lw1[j] + t1 * Lw1[512 + j] + Lb1[j], 0.0f);
                    #pragma unroll
                    for (int h = 0; h < 8; ++h) acc[h] += hh * Lw2[j * 8 + h];
                }
                #pragma unroll
                for (int h = 0; h < 8; ++h) part[tid * 8 + h] = acc[h];
            }
        }
        __syncthreads();
        if (tid < 225) {
            #pragma unroll
            for (int h = 0; h < 8; ++h)
                cpb[tid * 8 + h] = part[tid * 16 + h] + part[tid * 16 + 8 + h];
        }
        __syncthreads();
        // SWAPPED: frag holds S^T -> q from (lane&15, nt), k from (g,r, mt)
        for (int f = tid; f < 32768; f += 512) {
            int r = f & 3, lane = (f >> 2) & 63, nt = (f >> 8) & 3, mt = (f >> 10) & 3, h = (f >> 12) & 7;
            int k = mt * 16 + ((lane >> 4) << 2) + r;
            int q = nt * 16 + (lane & 15);
            int idx = ((q >> 3) - (k >> 3) + 7) * 15 + ((q & 7) - (k & 7) + 7);
            float c = cpb[idx * 8 + h];
            biasfrag[f] = 16.0f / (1.0f + expf(-c));
        }
    } else {
        int base = (blockIdx.x - 1) * 512 + tid;
        const int stride = 128 * 512;
        for (int i = base; i < 768 * 256; i += stride) {
            int n = i >> 8, k = i & 255;
            w_t[i] = (f16)qkv_w[k * 768 + n];     // w_t[n][k] = W[k][n]
        }
        for (int i = base; i < 256 * 256; i += stride) {
            int n = i >> 8, k = i & 255;
            p_t[i] = (f16)proj_w[k * 256 + n];
        }
    }
}

// ---------------- fused main: block = window, wave = head.
// LDS: [0,32K) xt[64 pix][256 ch] (GEMM) -> per-wave 4K vT slices (PV) -> ot (proj)
//      [32K,64K) 8 x 4K wave-private bounce (q/k frags, then P chunks)
__global__ __launch_bounds__(512) void k_fused(
    const float* __restrict__ x, const f16* __restrict__ w_t,
    const float* __restrict__ q_bias, const float* __restrict__ v_bias,
    const float* __restrict__ scale, const float* __restrict__ biasfrag,
    const f16* __restrict__ p_t, const float* __restrict__ proj_b,
    float* __restrict__ out)
{
    __shared__ char L[65536];
    const int tid = threadIdx.x;
    const int lane = tid & 63;
    const int h = tid >> 6;                   // wave = head
    const int l15 = lane & 15, g = lane >> 4;
    const int bw = blockIdx.x;
    const int win = bw & 1023, b = bw >> 10;
    const int wh = win >> 5, ww = win & 31;
    char* wb = L + 32768 + (h << 12);         // wave bounce
    char* vtr = L + (h << 12);                // wave vT slice (xt region, dead after GEMM)
    const f32x4 fz = {0.f, 0.f, 0.f, 0.f};
    const bool boundary = (wh == 31) || (ww == 31);

    // ---- phase 0: stage the window's 64 pixels (rolled coords), f32->f16
    {
        int pos = tid >> 3, tc = tid & 7;
        int i2 = ((wh << 3) + (pos >> 3) + 4) & 255;
        int j2 = ((ww << 3) + (pos & 7) + 4) & 255;
        const float* xr = x + ((((long)b << 8) + i2) * 256 + j2) * 256;
        int swz = (pos & 7) << 4;
        #pragma unroll
        for (int rep = 0; rep < 4; ++rep) {
            int ch = rep * 64 + tc * 8;
            float4 v0 = *reinterpret_cast<const float4*>(xr + ch);
            float4 v1 = *reinterpret_cast<const float4*>(xr + ch + 4);
            f16x8 hv = { (f16)v0.x, (f16)v0.y, (f16)v0.z, (f16)v0.w,
                         (f16)v1.x, (f16)v1.y, (f16)v1.z, (f16)v1.w };
            *reinterpret_cast<f16x8*>(L + ((pos * 512 + ch * 2) ^ swz)) = hv;
        }
    }
    __syncthreads();   // barrier 1

    f16x8 qa[4], kb[4];

    // swapped GEMM pass for q or k: acc[ct][mt] = C[ch, pix]; 32 AGPR peak
    auto qk_pass = [&](int p, float ls, bool addb, f16x8 frag[4]) {
        f32x4 acc[2][4];
        #pragma unroll
        for (int i = 0; i < 2; ++i)
            #pragma unroll
            for (int j = 0; j < 4; ++j) acc[i][j] = fz;
        #pragma unroll
        for (int ks = 0; ks < 8; ++ks) {
            f16x8 xf[4], wf[2];
            #pragma unroll
            for (int mt = 0; mt < 4; ++mt) {
                int row = mt * 16 + l15;
                xf[mt] = *reinterpret_cast<const f16x8*>(
                    L + ((row * 512 + ks * 64 + g * 16) ^ ((row & 7) << 4)));
            }
            #pragma unroll
            for (int ct = 0; ct < 2; ++ct)
                wf[ct] = *reinterpret_cast<const f16x8*>(
                    w_t + ((p << 8) + (h << 5) + ct * 16 + l15) * 256 + ks * 32 + g * 8);
            #pragma unroll
            for (int ct = 0; ct < 2; ++ct)
                #pragma unroll
                for (int mt = 0; mt < 4; ++mt)
                    acc[ct][mt] = __builtin_amdgcn_mfma_f32_16x16x32_f16(wf[ct], xf[mt], acc[ct][mt], 0, 0, 0);
        }
        float qb0[4], qb1[4];
        #pragma unroll
        for (int r = 0; r < 4; ++r) {
            qb0[r] = addb ? q_bias[(h << 5) + (g << 2) + r] : 0.f;
            qb1[r] = addb ? q_bias[(h << 5) + 16 + (g << 2) + r] : 0.f;
        }
        #pragma unroll
        for (int nt = 0; nt < 4; ++nt) {
            int pix = nt * 16 + l15;
            float t0[4], t1[4], s2 = 0.f;
            #pragma unroll
            for (int r = 0; r < 4; ++r) {
                t0[r] = acc[0][nt][r] + qb0[r];
                t1[r] = acc[1][nt][r] + qb1[r];
                s2 += t0[r] * t0[r] + t1[r] * t1[r];
            }
            s2 += __shfl_xor(s2, 16); s2 += __shfl_xor(s2, 32);
            float iv = ls / sqrtf(fmaxf(s2, EPS_L2));
            int sw = (pix & 7) << 4;
            f16x4 p0 = { (f16)(t0[0] * iv), (f16)(t0[1] * iv), (f16)(t0[2] * iv), (f16)(t0[3] * iv) };
            f16x4 p1 = { (f16)(t1[0] * iv), (f16)(t1[1] * iv), (f16)(t1[2] * iv), (f16)(t1[3] * iv) };
            *reinterpret_cast<f16x4*>(wb + ((pix * 64 + (g << 3)) ^ sw)) = p0;
            *reinterpret_cast<f16x4*>(wb + ((pix * 64 + 32 + (g << 3)) ^ sw)) = p1;
        }
        #pragma unroll
        for (int nt = 0; nt < 4; ++nt)
            frag[nt] = *reinterpret_cast<const f16x8*>(
                wb + (((nt * 16 + l15) * 64 + g * 16) ^ ((l15 & 7) << 4)));
    };

    // ---- phase 1a/1b: q then k (32 AGPR each; sched_barrier kills cross-pass
    // accumulator overlap so the AGPR high-water mark stays ~32)
    qk_pass(0, __expf(fminf(scale[h], LOG100)), true, qa);
    __builtin_amdgcn_sched_barrier(0);
    qk_pass(1, 1.0f, false, kb);
    __builtin_amdgcn_sched_barrier(0);

    // ---- phase 1c: v GEMM (normal orient, 32 AGPR); vT -> xt-region slice
    {
        f32x4 av[4][2];
        #pragma unroll
        for (int mt = 0; mt < 4; ++mt) { av[mt][0] = fz; av[mt][1] = fz; }
        #pragma unroll
        for (int ks = 0; ks < 8; ++ks) {
            f16x8 xf[4], wv[2];
            #pragma unroll
            for (int mt = 0; mt < 4; ++mt) {
                int row = mt * 16 + l15;
                xf[mt] = *reinterpret_cast<const f16x8*>(
                    L + ((row * 512 + ks * 64 + g * 16) ^ ((row & 7) << 4)));
            }
            #pragma unroll
            for (int nt = 0; nt < 2; ++nt)
                wv[nt] = *reinterpret_cast<const f16x8*>(
                    w_t + (512 + (h << 5) + nt * 16 + l15) * 256 + ks * 32 + g * 8);
            #pragma unroll
            for (int mt = 0; mt < 4; ++mt)
                #pragma unroll
                for (int nt = 0; nt < 2; ++nt)
                    av[mt][nt] = __builtin_amdgcn_mfma_f32_16x16x32_f16(xf[mt], wv[nt], av[mt][nt], 0, 0, 0);
        }
        __syncthreads();   // barrier 2: ALL xt reads done; xt region becomes vT
        float b0 = v_bias[(h << 5) + l15], b1 = v_bias[(h << 5) + 16 + l15];
        #pragma unroll
        for (int mt = 0; mt < 4; ++mt)
            #pragma unroll
            for (int nt = 0; nt < 2; ++nt) {
                float bsel = nt ? b1 : b0;
                f32x4 avv = av[mt][nt];
                f16x4 pk = { (f16)(avv[0] + bsel), (f16)(avv[1] + bsel),
                             (f16)(avv[2] + bsel), (f16)(avv[3] + bsel) };
                int u = nt * 16 + l15;
                int pix0 = mt * 16 + (g << 2);
                *reinterpret_cast<f16x4*>(vtr + ((u * 128 + pix0 * 2) ^ ((u & 7) << 4))) = pk;
            }
    }
    __builtin_amdgcn_sched_barrier(0);

    // ---- phase 2: S^T = mfma(K,Q); lane-local softmax; P chunked 32 q-rows
    f16x4 oh[4][2];
    #pragma unroll
    for (int c = 0; c < 2; ++c) {
        #pragma unroll
        for (int n2 = 0; n2 < 2; ++n2) {
            const int nt = c * 2 + n2;
            const int qrow = nt * 16 + l15;
            f32x4 st[4];
            #pragma unroll
            for (int mt = 0; mt < 4; ++mt)
                st[mt] = __builtin_amdgcn_mfma_f32_16x16x32_f16(kb[mt], qa[nt], fz, 0, 0, 0);
            #pragma unroll
            for (int mt = 0; mt < 4; ++mt)
                st[mt] += *reinterpret_cast<const f32x4*>(
                    biasfrag + ((((h * 4 + mt) * 4 + nt) * 64 + lane) << 2));
            if (boundary) {
                int lq = seg2((wh << 3) + (qrow >> 3)) * 3 + seg2((ww << 3) + (qrow & 7));
                #pragma unroll
                for (int mt = 0; mt < 4; ++mt)
                    #pragma unroll
                    for (int r = 0; r < 4; ++r) {
                        int k = mt * 16 + (g << 2) + r;
                        int lk = seg2((wh << 3) + (k >> 3)) * 3 + seg2((ww << 3) + (k & 7));
                        if (lq != lk) st[mt][r] -= 100.0f;
                    }
            }
            float mx = st[0][0];
            #pragma unroll
            for (int mt = 0; mt < 4; ++mt)
                #pragma unroll
                for (int r = 0; r < 4; ++r) mx = fmaxf(mx, st[mt][r]);
            mx = fmaxf(mx, __shfl_xor(mx, 16));
            mx = fmaxf(mx, __shfl_xor(mx, 32));
            float sm = 0.f;
            #pragma unroll
            for (int mt = 0; mt < 4; ++mt)
                #pragma unroll
                for (int r = 0; r < 4; ++r) {
                    float e = __expf(st[mt][r] - mx);
                    st[mt][r] = e;
                    sm += e;
                }
            sm += __shfl_xor(sm, 16);
            sm += __shfl_xor(sm, 32);
            float inv = 1.0f / sm;
            int sw = (qrow & 7) << 4;
            int rowb = (qrow & 31) * 128;     // local row in 4KB chunk
            #pragma unroll
            for (int mt = 0; mt < 4; ++mt) {
                f16x4 pk = { (f16)(st[mt][0] * inv), (f16)(st[mt][1] * inv),
                             (f16)(st[mt][2] * inv), (f16)(st[mt][3] * inv) };
                *reinterpret_cast<f16x4*>(wb + ((rowb + mt * 32 + (g << 3)) ^ sw)) = pk;
            }
        }
        // PV for this chunk (q-row tiles c*2, c*2+1); vf reloaded per chunk
        #pragma unroll
        for (int m2 = 0; m2 < 2; ++m2) {
            const int mt = c * 2 + m2;
            int row = m2 * 16 + l15;
            int swz = (row & 7) << 4;
            f16x8 pa0 = *reinterpret_cast<const f16x8*>(wb + ((row * 128 + g * 16) ^ swz));
            f16x8 pa1 = *reinterpret_cast<const f16x8*>(wb + ((row * 128 + 64 + g * 16) ^ swz));
            #pragma unroll
            for (int nt = 0; nt < 2; ++nt) {
                f16x8 vf0 = *reinterpret_cast<const f16x8*>(
                    vtr + (((nt * 16 + l15) * 128 + g * 16) ^ ((l15 & 7) << 4)));
                f16x8 vf1 = *reinterpret_cast<const f16x8*>(
                    vtr + (((nt * 16 + l15) * 128 + 64 + g * 16) ^ ((l15 & 7) << 4)));
                f32x4 t = __builtin_amdgcn_mfma_f32_16x16x32_f16(pa0, vf0, fz, 0, 0, 0);
                t = __builtin_amdgcn_mfma_f32_16x16x32_f16(pa1, vf1, t, 0, 0, 0);
                oh[mt][nt] = f16x4{ (f16)t[0], (f16)t[1], (f16)t[2], (f16)t[3] };
            }
        }
    }
    __builtin_amdgcn_sched_barrier(0);

    // ---- phase 3: O -> ot (xt region), fused proj, direct store
    __syncthreads();   // barrier 3: all PV done; vT region becomes ot
    #pragma unroll
    for (int mt = 0; mt < 4; ++mt)
        #pragma unroll
        for (int r = 0; r < 4; ++r) {
            int q = mt * 16 + (g << 2) + r;
            #pragma unroll
            for (int nt = 0; nt < 2; ++nt) {
                int ch = (h << 5) + nt * 16 + l15;
                *reinterpret_cast<f16*>(L + ((q * 512 + ch * 2) ^ ((q & 7) << 4))) =
                    oh[mt][nt][r];
            }
        }
    __syncthreads();   // barrier 4

    const int c0 = h << 5;
    f32x4 pc[4][2];
    #pragma unroll
    for (int mt = 0; mt < 4; ++mt) { pc[mt][0] = fz; pc[mt][1] = fz; }
    #pragma unroll
    for (int ks = 0; ks < 8; ++ks) {
        f16x8 a[4], bfr[2];
        #pragma unroll
        for (int mt = 0; mt < 4; ++mt) {
            int q = mt * 16 + l15;
            a[mt] = *reinterpret_cast<const f16x8*>(
                L + ((q * 512 + ks * 64 + g * 16) ^ ((q & 7) << 4)));
        }
        #pragma unroll
        for (int nt = 0; nt < 2; ++nt)
            bfr[nt] = *reinterpret_cast<const f16x8*>(
                p_t + (c0 + nt * 16 + l15) * 256 + ks * 32 + g * 8);
        #pragma unroll
        for (int mt = 0; mt < 4; ++mt)
            #pragma unroll
            for (int nt = 0; nt < 2; ++nt)
                pc[mt][nt] = __builtin_amdgcn_mfma_f32_16x16x32_f16(a[mt], bfr[nt], pc[mt][nt], 0, 0, 0);
    }
    float pb0 = proj_b[c0 + l15], pb1 = proj_b[c0 + 16 + l15];
    #pragma unroll
    for (int mt = 0; mt < 4; ++mt)
        #pragma unroll
        for (int r = 0; r < 4; ++r) {
            int q = mt * 16 + (g << 2) + r;
            int i = ((wh << 3) + (q >> 3) + 4) & 255;   // roll(+4) un-partition
            int j = ((ww << 3) + (q & 7) + 4) & 255;
            long addr = (((long)b * 256 + i) * 256 + j) * 256;
            out[addr + c0 + l15]      = pc[mt][0][r] + pb0;
            out[addr + c0 + 16 + l15] = pc[mt][1][r] + pb1;
        }
}

extern "C" void kernel_launch(void* const* d_in, const int* in_sizes, int n_in,
                              void* d_out, int out_size, void* d_ws, size_t ws_size,
                              hipStream_t stream) {
    const float* x      = (const float*)d_in[0];
    const float* qkv_w  = (const float*)d_in[1];
    const float* q_bias = (const float*)d_in[2];
    const float* v_bias = (const float*)d_in[3];
    const float* scale  = (const float*)d_in[4];
    const float* cpb_w1 = (const float*)d_in[5];
    const float* cpb_b1 = (const float*)d_in[6];
    const float* cpb_w2 = (const float*)d_in[7];
    const float* proj_w = (const float*)d_in[8];
    const float* proj_b = (const float*)d_in[9];
    float* out = (float*)d_out;

    char* ws = (char*)d_ws;
    float* biasfrag = (float*)(ws);                         // 128 KiB
    f16* w_t  = (f16*)(ws + 131072);                        // 384 KiB
    f16* p_t  = (f16*)(ws + 524288);                        // 128 KiB

    hipLaunchKernelGGL(k_prep, dim3(129), dim3(512), 0, stream,
                       cpb_w1, cpb_b1, cpb_w2, qkv_w, proj_w, biasfrag, w_t, p_t);
    hipLaunchKernelGGL(k_fused, dim3(2048), dim3(512), 0, stream,
                       x, w_t, q_bias, v_bias, scale, biasfrag, p_t, proj_b, out);
}